// Round 9
// baseline (189.600 us; speedup 1.0000x reference)
//
#include <hip/hip_runtime.h>
#include <hip/hip_bf16.h>
#include <cstdint>
#include <cstddef>

constexpr int BATCH = 2;
constexpr int C_IN  = 64;
constexpr int CK    = 1024;   // C_IN * N_FILTERS
constexpr int C_OUT = 256;
constexpr int CHUNK = 32;     // edges staged per LDS pass (avg degree = 12)

using bf16x8 = __attribute__((ext_vector_type(8))) short;
using f32x4  = __attribute__((ext_vector_type(4))) float;

#define GLOAD_LDS16(g, s) \
    __builtin_amdgcn_global_load_lds((const __attribute__((address_space(1))) void*)(g), \
                                     (__attribute__((address_space(3))) void*)(s), 16, 0, 0)

// ---------------- CSR build ----------------
__global__ void hist_kernel(const int* __restrict__ dst, int* __restrict__ counts, int E) {
    int e = blockIdx.x * blockDim.x + threadIdx.x;
    if (e < E) atomicAdd(&counts[dst[e]], 1);
}

// single-block scan, wave-register version: wave w owns 640 contiguous elements
// (10 groups of 64 in registers), 3 barriers total per 10240-tile.
__global__ __launch_bounds__(1024)
void scan_kernel(const int* __restrict__ counts, int* __restrict__ offsets, int n) {
    __shared__ int wtot_s[16];
    __shared__ int carry_s;
    const int t = threadIdx.x;
    const int lane = t & 63;
    const int w = t >> 6;
    if (t == 0) carry_s = 0;
    __syncthreads();
    for (int base = 0; base < n; base += 10240) {
        int v[10], ex[10];
        #pragma unroll
        for (int g = 0; g < 10; ++g) {
            const int idx = base + w * 640 + g * 64 + lane;
            v[g] = (idx < n) ? counts[idx] : 0;
        }
        int run = 0;
        #pragma unroll
        for (int g = 0; g < 10; ++g) {
            int x = v[g];
            #pragma unroll
            for (int off = 1; off < 64; off <<= 1) {
                int y = __shfl_up(x, off, 64);
                if (lane >= off) x += y;
            }
            ex[g] = run + x - v[g];          // exclusive within wave
            run += __shfl(x, 63, 64);        // add group total
        }
        if (lane == 63) wtot_s[w] = run;
        __syncthreads();
        int wpre = 0, tot = 0;
        #pragma unroll
        for (int i = 0; i < 16; ++i) {
            const int s = wtot_s[i];
            if (i < w) wpre += s;
            tot += s;
        }
        const int carry = carry_s;
        #pragma unroll
        for (int g = 0; g < 10; ++g) {
            const int idx = base + w * 640 + g * 64 + lane;
            if (idx < n) offsets[idx] = carry + wpre + ex[g];
        }
        __syncthreads();                      // all reads of carry_s done
        if (t == 0) carry_s = carry + tot;
        __syncthreads();
    }
    if (t == 0) offsets[n] = carry_s;
}

__global__ void scatter_kernel(const int* __restrict__ dst, const int* __restrict__ src,
                               const int* __restrict__ offsets,
                               int* __restrict__ cursors, int* __restrict__ sorted_src, int E) {
    int e = blockIdx.x * blockDim.x + threadIdx.x;
    if (e < E) {
        const int d = dst[e];
        const int p = atomicAdd(&cursors[d], 1);
        sorted_src[offsets[d] + p] = src[e];
    }
}

// ---------------- prep: W_feat f32->bf16  +  W_dir/b_dir pack to float4 ----------------
__global__ __launch_bounds__(256)
void prep_kernel(const float* __restrict__ Wf, __hip_bfloat16* __restrict__ Wb,
                 const float* __restrict__ W_dir, const float* __restrict__ b_dir,
                 float4* __restrict__ Wp) {
    const int id = blockIdx.x * 256 + threadIdx.x;
    const int i = id * 4;
    const float4 v = *reinterpret_cast<const float4*>(Wf + i);
    __hip_bfloat162 a, b;
    a.x = __float2bfloat16(v.x); a.y = __float2bfloat16(v.y);
    b.x = __float2bfloat16(v.z); b.y = __float2bfloat16(v.w);
    *reinterpret_cast<__hip_bfloat162*>(Wb + i)     = a;
    *reinterpret_cast<__hip_bfloat162*>(Wb + i + 2) = b;
    if (id < CK)
        Wp[id] = make_float4(W_dir[id * 3 + 0], W_dir[id * 3 + 1], W_dir[id * 3 + 2], b_dir[id]);
}

// ---------------- per-node edge aggregation -> bf16 agg ----------------
// One block per node, both batches. Thread t owns k in {2t,2t+1,2t+512,2t+513}, c0=(2t)&63.
// Chunks padded to multiple of 4 (zeroed dir/feats rows -> exact zero contribution),
// inner loop unrolled x4 so LDS addresses fold to base+immediate.
__global__ __launch_bounds__(256)
void agg_kernel(const float* __restrict__ feats, const float* __restrict__ pos,
                const int* __restrict__ sorted_src, const int* __restrict__ offsets,
                const float4* __restrict__ Wp,
                __hip_bfloat16* __restrict__ agg, int N) {
    __shared__ float  feats_s[BATCH][CHUNK][C_IN];   // 16 KB
    __shared__ float4 dir_s[BATCH][CHUNK];           // 1 KB
    __shared__ int    sh_s[CHUNK];

    const int n = blockIdx.x;
    const int t = threadIdx.x;
    const int c0 = (2 * t) & 63;

    float4 wv[4];
    wv[0] = Wp[2 * t];       wv[1] = Wp[2 * t + 1];
    wv[2] = Wp[2 * t + 512]; wv[3] = Wp[2 * t + 513];

    float cx[BATCH], cy[BATCH], cz[BATCH];
    #pragma unroll
    for (int b = 0; b < BATCH; ++b) {
        const float* pb = pos + ((size_t)b * N + n) * 3;
        cx[b] = pb[0]; cy[b] = pb[1]; cz[b] = pb[2];
    }

    float acc[BATCH][4] = {};
    const int beg = offsets[n], end = offsets[n + 1];

    for (int j0 = beg; j0 < end; j0 += CHUNK) {
        const int cnt  = min(CHUNK, end - j0);
        const int cnt4 = (cnt + 3) & ~3;
        // ---- phase A1: indices + directions (+ zero pad rows) ----
        if (t < cnt) {
            const int s = sorted_src[j0 + t];
            sh_s[t] = s;
            #pragma unroll
            for (int b = 0; b < BATCH; ++b) {
                const float* ps = pos + ((size_t)b * N + s) * 3;
                dir_s[b][t] = make_float4(ps[0] - cx[b], ps[1] - cy[b], ps[2] - cz[b], 0.f);
            }
        } else if (t < cnt4) {
            dir_s[0][t] = make_float4(0.f, 0.f, 0.f, 0.f);
            dir_s[1][t] = make_float4(0.f, 0.f, 0.f, 0.f);
        }
        __syncthreads();    // sh_s visible
        // ---- phase A2: feature rows, float4-vectorized (zeros for pad rows) ----
        #pragma unroll
        for (int b = 0; b < BATCH; ++b) {
            const float* fb = feats + (size_t)b * N * C_IN;
            for (int idx = t; idx < cnt4 * 16; idx += 256) {
                const int e = idx >> 4, q = idx & 15;
                float4 v = make_float4(0.f, 0.f, 0.f, 0.f);
                if (e < cnt) v = *reinterpret_cast<const float4*>(fb + (size_t)sh_s[e] * C_IN + q * 4);
                *reinterpret_cast<float4*>(&feats_s[b][e][q * 4]) = v;
            }
        }
        __syncthreads();    // staged data ready
        // ---- phase B: unrolled x4 ----
        for (int j = 0; j < cnt4; j += 4) {
            #pragma unroll
            for (int jj = 0; jj < 4; ++jj) {
                #pragma unroll
                for (int b = 0; b < BATCH; ++b) {
                    const float4 d = dir_s[b][j + jj];
                    const float2 f = *reinterpret_cast<const float2*>(&feats_s[b][j + jj][c0]);
                    #pragma unroll
                    for (int u = 0; u < 4; ++u) {
                        const float a = fmaxf(fmaf(d.x, wv[u].x,
                                             fmaf(d.y, wv[u].y,
                                             fmaf(d.z, wv[u].z, wv[u].w))), 0.f);
                        acc[b][u] = fmaf((u & 1) ? f.y : f.x, a, acc[b][u]);
                    }
                }
            }
        }
        __syncthreads();    // before next chunk overwrites LDS
    }

    // self term + store
    #pragma unroll
    for (int b = 0; b < BATCH; ++b) {
        const float2 fs = *reinterpret_cast<const float2*>(
            feats + ((size_t)b * N + n) * C_IN + c0);
        #pragma unroll
        for (int u = 0; u < 4; ++u)
            acc[b][u] += ((u & 1) ? fs.y : fs.x) * fmaxf(wv[u].w, 0.f);
        __hip_bfloat16* dst = agg + ((size_t)b * N + n) * CK;
        __hip_bfloat162 v01, v23;
        v01.x = __float2bfloat16(acc[b][0]); v01.y = __float2bfloat16(acc[b][1]);
        v23.x = __float2bfloat16(acc[b][2]); v23.y = __float2bfloat16(acc[b][3]);
        *reinterpret_cast<__hip_bfloat162*>(dst + 2 * t)       = v01;
        *reinterpret_cast<__hip_bfloat162*>(dst + 2 * t + 512) = v23;
    }
}

// ---------------- MFMA GEMM, 64x64 tile, double-buffered 2-phase prefetch -------------
// BK=64, 4 waves (2x2), global_load_lds + both-sides XOR swizzle (rule 21).
// STAGE(next) issued before compute(cur); __syncthreads() drains after compute phase.
__global__ __launch_bounds__(256)
void gemm_kernel(const __hip_bfloat16* __restrict__ agg, const __hip_bfloat16* __restrict__ W,
                 const float* __restrict__ bf, float* __restrict__ out, int M) {
    __shared__ __hip_bfloat16 As[2][64 * 64];
    __shared__ __hip_bfloat16 Bs[2][64 * 64];
    const int t    = threadIdx.x;
    const int lane = t & 63;
    const int w    = t >> 6;
    const int q    = lane & 15;
    const int h    = lane >> 4;
    const int r0   = blockIdx.x * 64;
    const int c0   = blockIdx.y * 64;

    const int lrow    = lane >> 3;
    const int kschunk = (lane & 7) ^ lrow;   // logical k-chunk fetched into physical chunk lane&7

    f32x4 acc[2][2];
    #pragma unroll
    for (int mi = 0; mi < 2; ++mi)
        #pragma unroll
        for (int nj = 0; nj < 2; ++nj)
            #pragma unroll
            for (int r = 0; r < 4; ++r) acc[mi][nj][r] = 0.f;

    auto stage = [&](int buf, int k0) {
        #pragma unroll
        for (int i2 = 0; i2 < 2; ++i2) {
            const int seg = i2 * 4 + w;          // 0..7, wave-uniform; 8 rows each
            const int row = seg * 8 + lrow;
            GLOAD_LDS16(agg + (size_t)(r0 + row) * CK + k0 + 8 * kschunk, &As[buf][seg * 512]);
            GLOAD_LDS16(W   + (size_t)(c0 + row) * CK + k0 + 8 * kschunk, &Bs[buf][seg * 512]);
        }
    };

    stage(0, 0);
    __syncthreads();                              // prologue drain

    for (int ks = 0; ks < 16; ++ks) {
        const int cur = ks & 1;
        if (ks < 15) stage(cur ^ 1, (ks + 1) * 64);   // prefetch next tile

        #pragma unroll
        for (int kk = 0; kk < 2; ++kk) {
            bf16x8 af[2], bfr[2];
            #pragma unroll
            for (int mi = 0; mi < 2; ++mi) {
                const int row = (w >> 1) * 32 + mi * 16 + q;
                const int ch  = (kk * 4 + h) ^ (row & 7);
                af[mi] = *reinterpret_cast<const bf16x8*>(&As[cur][row * 64 + ch * 8]);
            }
            #pragma unroll
            for (int nj = 0; nj < 2; ++nj) {
                const int row = (w & 1) * 32 + nj * 16 + q;
                const int ch  = (kk * 4 + h) ^ (row & 7);
                bfr[nj] = *reinterpret_cast<const bf16x8*>(&Bs[cur][row * 64 + ch * 8]);
            }
            #pragma unroll
            for (int mi = 0; mi < 2; ++mi)
                #pragma unroll
                for (int nj = 0; nj < 2; ++nj)
                    acc[mi][nj] = __builtin_amdgcn_mfma_f32_16x16x32_bf16(
                        af[mi], bfr[nj], acc[mi][nj], 0, 0, 0);
        }
        __syncthreads();   // drains prefetch loads (flew during compute) + reuse barrier
    }

    #pragma unroll
    for (int mi = 0; mi < 2; ++mi) {
        #pragma unroll
        for (int nj = 0; nj < 2; ++nj) {
            const int col  = c0 + (w & 1) * 32 + nj * 16 + q;
            const float bias = bf[col];
            #pragma unroll
            for (int r = 0; r < 4; ++r) {
                const int row = r0 + (w >> 1) * 32 + mi * 16 + h * 4 + r;
                if (row < M)
                    out[(size_t)row * C_OUT + col] = fmaxf(acc[mi][nj][r] + bias, 0.f);
            }
        }
    }
}

extern "C" void kernel_launch(void* const* d_in, const int* in_sizes, int n_in,
                              void* d_out, int out_size, void* d_ws, size_t ws_size,
                              hipStream_t stream) {
    const float* feats  = (const float*)d_in[0];
    const float* pos    = (const float*)d_in[1];
    const int*   esrc   = (const int*)d_in[2];
    const int*   edst   = (const int*)d_in[3];
    const float* W_dir  = (const float*)d_in[4];
    const float* b_dir  = (const float*)d_in[5];
    const float* W_feat = (const float*)d_in[6];
    const float* b_feat = (const float*)d_in[7];
    float* out = (float*)d_out;

    const int N = in_sizes[1] / (BATCH * 3);
    const int E = in_sizes[2];
    const int M = BATCH * N;
    const int MBLK = (M + 63) / 64;
    const int M_pad = MBLK * 64;           // staging reads up to M_pad rows

    char* ws = (char*)d_ws;
    size_t off = 0;
    auto alignup = [&](size_t a) { off = (off + a - 1) & ~(a - 1); };

    __hip_bfloat16* agg = (__hip_bfloat16*)(ws + off); off += (size_t)M_pad * CK * sizeof(__hip_bfloat16);
    alignup(256);
    __hip_bfloat16* Wb  = (__hip_bfloat16*)(ws + off); off += (size_t)C_OUT * CK * sizeof(__hip_bfloat16);
    alignup(256);
    float4* Wp = (float4*)(ws + off); off += (size_t)CK * sizeof(float4);
    alignup(256);
    int* counts  = (int*)(ws + off); off += (size_t)N * sizeof(int);
    int* cursors = (int*)(ws + off); off += (size_t)N * sizeof(int);   // contiguous with counts
    alignup(256);
    int* offsets = (int*)(ws + off); off += (size_t)(N + 1) * sizeof(int);
    alignup(256);
    int* sorted_src = (int*)(ws + off); off += (size_t)E * sizeof(int);

    hipMemsetAsync(counts, 0, (size_t)2 * N * sizeof(int), stream);  // counts + cursors
    hist_kernel<<<dim3((E + 255) / 256), dim3(256), 0, stream>>>(edst, counts, E);
    scan_kernel<<<dim3(1), dim3(1024), 0, stream>>>(counts, offsets, N);
    scatter_kernel<<<dim3((E + 255) / 256), dim3(256), 0, stream>>>(edst, esrc, offsets, cursors, sorted_src, E);
    prep_kernel<<<dim3(C_OUT * CK / 1024), dim3(256), 0, stream>>>(W_feat, Wb, W_dir, b_dir, Wp);
    agg_kernel<<<dim3(N), dim3(256), 0, stream>>>(feats, pos, sorted_src, offsets, Wp, agg, N);
    gemm_kernel<<<dim3(MBLK, C_OUT / 64), dim3(256), 0, stream>>>(agg, Wb, b_feat, out, M);
}

// Round 10
// 169.657 us; speedup vs baseline: 1.1175x; 1.1175x over previous
//
#include <hip/hip_runtime.h>
#include <hip/hip_bf16.h>
#include <cstdint>
#include <cstddef>

constexpr int BATCH = 2;
constexpr int C_IN  = 64;
constexpr int CK    = 1024;   // C_IN * N_FILTERS
constexpr int C_OUT = 256;
constexpr int CHUNK = 32;     // edges staged per LDS pass (avg degree = 12)
constexpr int AGG_BLOCKS = 2048;   // 8 blocks/CU exactly; grid-stride over nodes

using bf16x8 = __attribute__((ext_vector_type(8))) short;
using f32x4  = __attribute__((ext_vector_type(4))) float;

#define GLOAD_LDS16(g, s) \
    __builtin_amdgcn_global_load_lds((const __attribute__((address_space(1))) void*)(g), \
                                     (__attribute__((address_space(3))) void*)(s), 16, 0, 0)

// ---------------- CSR build ----------------
__global__ void hist_kernel(const int* __restrict__ dst, int* __restrict__ counts, int E) {
    int e = blockIdx.x * blockDim.x + threadIdx.x;
    if (e < E) atomicAdd(&counts[dst[e]], 1);
}

// single-block scan, wave-register version: wave w owns 640 contiguous elements
// (10 groups of 64 in registers); N=10000 fits one 10240-tile -> ~3 barriers total.
__global__ __launch_bounds__(1024)
void scan_kernel(const int* __restrict__ counts, int* __restrict__ offsets, int n) {
    __shared__ int wtot_s[16];
    __shared__ int carry_s;
    const int t = threadIdx.x;
    const int lane = t & 63;
    const int w = t >> 6;
    if (t == 0) carry_s = 0;
    __syncthreads();
    for (int base = 0; base < n; base += 10240) {
        int v[10], ex[10];
        #pragma unroll
        for (int g = 0; g < 10; ++g) {
            const int idx = base + w * 640 + g * 64 + lane;
            v[g] = (idx < n) ? counts[idx] : 0;
        }
        int run = 0;
        #pragma unroll
        for (int g = 0; g < 10; ++g) {
            int x = v[g];
            #pragma unroll
            for (int off = 1; off < 64; off <<= 1) {
                int y = __shfl_up(x, off, 64);
                if (lane >= off) x += y;
            }
            ex[g] = run + x - v[g];          // exclusive within wave
            run += __shfl(x, 63, 64);        // add group total
        }
        if (lane == 63) wtot_s[w] = run;
        __syncthreads();
        int wpre = 0, tot = 0;
        #pragma unroll
        for (int i = 0; i < 16; ++i) {
            const int s = wtot_s[i];
            if (i < w) wpre += s;
            tot += s;
        }
        const int carry = carry_s;
        #pragma unroll
        for (int g = 0; g < 10; ++g) {
            const int idx = base + w * 640 + g * 64 + lane;
            if (idx < n) offsets[idx] = carry + wpre + ex[g];
        }
        __syncthreads();                      // all reads of carry_s done
        if (t == 0) carry_s = carry + tot;
        __syncthreads();
    }
    if (t == 0) offsets[n] = carry_s;
}

__global__ void scatter_kernel(const int* __restrict__ dst, const int* __restrict__ src,
                               const int* __restrict__ offsets,
                               int* __restrict__ cursors, int* __restrict__ sorted_src, int E) {
    int e = blockIdx.x * blockDim.x + threadIdx.x;
    if (e < E) {
        const int d = dst[e];
        const int p = atomicAdd(&cursors[d], 1);
        sorted_src[offsets[d] + p] = src[e];
    }
}

// ---------------- prep: W_feat f32->bf16  +  W_dir/b_dir pack to float4 ----------------
__global__ __launch_bounds__(256)
void prep_kernel(const float* __restrict__ Wf, __hip_bfloat16* __restrict__ Wb,
                 const float* __restrict__ W_dir, const float* __restrict__ b_dir,
                 float4* __restrict__ Wp) {
    const int id = blockIdx.x * 256 + threadIdx.x;
    const int i = id * 4;
    const float4 v = *reinterpret_cast<const float4*>(Wf + i);
    __hip_bfloat162 a, b;
    a.x = __float2bfloat16(v.x); a.y = __float2bfloat16(v.y);
    b.x = __float2bfloat16(v.z); b.y = __float2bfloat16(v.w);
    *reinterpret_cast<__hip_bfloat162*>(Wb + i)     = a;
    *reinterpret_cast<__hip_bfloat162*>(Wb + i + 2) = b;
    if (id < CK)
        Wp[id] = make_float4(W_dir[id * 3 + 0], W_dir[id * 3 + 1], W_dir[id * 3 + 2], b_dir[id]);
}

// ---------------- per-node edge aggregation -> bf16 agg (R6 inner loop, persistent) ----
// Persistent blocks: Wp (16KB) loaded ONCE per block, then grid-stride over nodes.
// Thread t owns k in {2t,2t+1,2t+512,2t+513}; c0=(2t)&63. R6's simple runtime-bound
// inner loop (40 VGPR, occupancy-friendly) -- R9's unroll regressed via VGPR pressure.
__global__ __launch_bounds__(256)
void agg_kernel(const float* __restrict__ feats, const float* __restrict__ pos,
                const int* __restrict__ sorted_src, const int* __restrict__ offsets,
                const float4* __restrict__ Wp,
                __hip_bfloat16* __restrict__ agg, int N) {
    __shared__ float  feats_s[BATCH][CHUNK][C_IN];   // 16 KB
    __shared__ float4 dir_s[BATCH][CHUNK];           // 1 KB
    __shared__ int    sh_s[CHUNK];

    const int t = threadIdx.x;
    const int c0 = (2 * t) & 63;

    float4 wv[4];
    wv[0] = Wp[2 * t];       wv[1] = Wp[2 * t + 1];
    wv[2] = Wp[2 * t + 512]; wv[3] = Wp[2 * t + 513];

    for (int n = blockIdx.x; n < N; n += AGG_BLOCKS) {
        float cx[BATCH], cy[BATCH], cz[BATCH];
        #pragma unroll
        for (int b = 0; b < BATCH; ++b) {
            const float* pb = pos + ((size_t)b * N + n) * 3;
            cx[b] = pb[0]; cy[b] = pb[1]; cz[b] = pb[2];
        }

        float acc[BATCH][4] = {};
        const int beg = offsets[n], end = offsets[n + 1];

        for (int j0 = beg; j0 < end; j0 += CHUNK) {
            const int cnt = min(CHUNK, end - j0);
            // ---- phase A1: indices + directions ----
            if (t < cnt) {
                const int s = sorted_src[j0 + t];
                sh_s[t] = s;
                #pragma unroll
                for (int b = 0; b < BATCH; ++b) {
                    const float* ps = pos + ((size_t)b * N + s) * 3;
                    dir_s[b][t] = make_float4(ps[0] - cx[b], ps[1] - cy[b], ps[2] - cz[b], 0.f);
                }
            }
            __syncthreads();    // sh_s visible
            // ---- phase A2: feature rows, float4-vectorized ----
            #pragma unroll
            for (int b = 0; b < BATCH; ++b) {
                const float* fb = feats + (size_t)b * N * C_IN;
                for (int idx = t; idx < cnt * 16; idx += 256) {
                    const int e = idx >> 4, q = idx & 15;
                    *reinterpret_cast<float4*>(&feats_s[b][e][q * 4]) =
                        *reinterpret_cast<const float4*>(fb + (size_t)sh_s[e] * C_IN + q * 4);
                }
            }
            __syncthreads();    // staged data ready
            // ---- phase B ----
            #pragma unroll
            for (int b = 0; b < BATCH; ++b) {
                for (int j = 0; j < cnt; ++j) {
                    const float4 d = dir_s[b][j];
                    const float2 f = *reinterpret_cast<const float2*>(&feats_s[b][j][c0]);
                    #pragma unroll
                    for (int u = 0; u < 4; ++u) {
                        const float a = fmaxf(fmaf(d.x, wv[u].x,
                                             fmaf(d.y, wv[u].y,
                                             fmaf(d.z, wv[u].z, wv[u].w))), 0.f);
                        acc[b][u] = fmaf((u & 1) ? f.y : f.x, a, acc[b][u]);
                    }
                }
            }
            __syncthreads();    // before next chunk / next node overwrites LDS
        }

        // self term + store
        #pragma unroll
        for (int b = 0; b < BATCH; ++b) {
            const float2 fs = *reinterpret_cast<const float2*>(
                feats + ((size_t)b * N + n) * C_IN + c0);
            #pragma unroll
            for (int u = 0; u < 4; ++u)
                acc[b][u] += ((u & 1) ? fs.y : fs.x) * fmaxf(wv[u].w, 0.f);
            __hip_bfloat16* dst = agg + ((size_t)b * N + n) * CK;
            __hip_bfloat162 v01, v23;
            v01.x = __float2bfloat16(acc[b][0]); v01.y = __float2bfloat16(acc[b][1]);
            v23.x = __float2bfloat16(acc[b][2]); v23.y = __float2bfloat16(acc[b][3]);
            *reinterpret_cast<__hip_bfloat162*>(dst + 2 * t)       = v01;
            *reinterpret_cast<__hip_bfloat162*>(dst + 2 * t + 512) = v23;
        }
    }
}

// ---------------- MFMA GEMM, 64x64 tile, single-buffer (R6 exact) ----------------
// BK=64, 4 waves (2x2), global_load_lds + both-sides XOR swizzle (rule 21).
__global__ __launch_bounds__(256)
void gemm_kernel(const __hip_bfloat16* __restrict__ agg, const __hip_bfloat16* __restrict__ W,
                 const float* __restrict__ bf, float* __restrict__ out, int M) {
    __shared__ __hip_bfloat16 As[64 * 64];
    __shared__ __hip_bfloat16 Bs[64 * 64];
    const int t    = threadIdx.x;
    const int lane = t & 63;
    const int w    = t >> 6;
    const int q    = lane & 15;
    const int h    = lane >> 4;
    const int r0   = blockIdx.x * 64;
    const int c0   = blockIdx.y * 64;

    const int lrow    = lane >> 3;
    const int kschunk = (lane & 7) ^ lrow;   // logical k-chunk fetched into physical chunk lane&7

    f32x4 acc[2][2];
    #pragma unroll
    for (int mi = 0; mi < 2; ++mi)
        #pragma unroll
        for (int nj = 0; nj < 2; ++nj)
            #pragma unroll
            for (int r = 0; r < 4; ++r) acc[mi][nj][r] = 0.f;

    for (int k0 = 0; k0 < CK; k0 += 64) {
        #pragma unroll
        for (int i2 = 0; i2 < 2; ++i2) {
            const int seg = i2 * 4 + w;          // 0..7, wave-uniform; 8 rows each
            const int row = seg * 8 + lrow;
            GLOAD_LDS16(agg + (size_t)(r0 + row) * CK + k0 + 8 * kschunk, As + seg * 512);
            GLOAD_LDS16(W   + (size_t)(c0 + row) * CK + k0 + 8 * kschunk, Bs + seg * 512);
        }
        __syncthreads();

        #pragma unroll
        for (int kk = 0; kk < 2; ++kk) {
            bf16x8 af[2], bfr[2];
            #pragma unroll
            for (int mi = 0; mi < 2; ++mi) {
                const int row = (w >> 1) * 32 + mi * 16 + q;
                const int ch  = (kk * 4 + h) ^ (row & 7);
                af[mi] = *reinterpret_cast<const bf16x8*>(As + row * 64 + ch * 8);
            }
            #pragma unroll
            for (int nj = 0; nj < 2; ++nj) {
                const int row = (w & 1) * 32 + nj * 16 + q;
                const int ch  = (kk * 4 + h) ^ (row & 7);
                bfr[nj] = *reinterpret_cast<const bf16x8*>(Bs + row * 64 + ch * 8);
            }
            #pragma unroll
            for (int mi = 0; mi < 2; ++mi)
                #pragma unroll
                for (int nj = 0; nj < 2; ++nj)
                    acc[mi][nj] = __builtin_amdgcn_mfma_f32_16x16x32_bf16(
                        af[mi], bfr[nj], acc[mi][nj], 0, 0, 0);
        }
        __syncthreads();
    }

    #pragma unroll
    for (int mi = 0; mi < 2; ++mi) {
        #pragma unroll
        for (int nj = 0; nj < 2; ++nj) {
            const int col  = c0 + (w & 1) * 32 + nj * 16 + q;
            const float bias = bf[col];
            #pragma unroll
            for (int r = 0; r < 4; ++r) {
                const int row = r0 + (w >> 1) * 32 + mi * 16 + h * 4 + r;
                if (row < M)
                    out[(size_t)row * C_OUT + col] = fmaxf(acc[mi][nj][r] + bias, 0.f);
            }
        }
    }
}

extern "C" void kernel_launch(void* const* d_in, const int* in_sizes, int n_in,
                              void* d_out, int out_size, void* d_ws, size_t ws_size,
                              hipStream_t stream) {
    const float* feats  = (const float*)d_in[0];
    const float* pos    = (const float*)d_in[1];
    const int*   esrc   = (const int*)d_in[2];
    const int*   edst   = (const int*)d_in[3];
    const float* W_dir  = (const float*)d_in[4];
    const float* b_dir  = (const float*)d_in[5];
    const float* W_feat = (const float*)d_in[6];
    const float* b_feat = (const float*)d_in[7];
    float* out = (float*)d_out;

    const int N = in_sizes[1] / (BATCH * 3);
    const int E = in_sizes[2];
    const int M = BATCH * N;
    const int MBLK = (M + 63) / 64;
    const int M_pad = MBLK * 64;           // staging reads up to M_pad rows

    char* ws = (char*)d_ws;
    size_t off = 0;
    auto alignup = [&](size_t a) { off = (off + a - 1) & ~(a - 1); };

    __hip_bfloat16* agg = (__hip_bfloat16*)(ws + off); off += (size_t)M_pad * CK * sizeof(__hip_bfloat16);
    alignup(256);
    __hip_bfloat16* Wb  = (__hip_bfloat16*)(ws + off); off += (size_t)C_OUT * CK * sizeof(__hip_bfloat16);
    alignup(256);
    float4* Wp = (float4*)(ws + off); off += (size_t)CK * sizeof(float4);
    alignup(256);
    int* counts  = (int*)(ws + off); off += (size_t)N * sizeof(int);
    int* cursors = (int*)(ws + off); off += (size_t)N * sizeof(int);   // contiguous with counts
    alignup(256);
    int* offsets = (int*)(ws + off); off += (size_t)(N + 1) * sizeof(int);
    alignup(256);
    int* sorted_src = (int*)(ws + off); off += (size_t)E * sizeof(int);

    hipMemsetAsync(counts, 0, (size_t)2 * N * sizeof(int), stream);  // counts + cursors
    hist_kernel<<<dim3((E + 255) / 256), dim3(256), 0, stream>>>(edst, counts, E);
    scan_kernel<<<dim3(1), dim3(1024), 0, stream>>>(counts, offsets, N);
    scatter_kernel<<<dim3((E + 255) / 256), dim3(256), 0, stream>>>(edst, esrc, offsets, cursors, sorted_src, E);
    prep_kernel<<<dim3(C_OUT * CK / 1024), dim3(256), 0, stream>>>(W_feat, Wb, W_dir, b_dir, Wp);
    agg_kernel<<<dim3(AGG_BLOCKS), dim3(256), 0, stream>>>(feats, pos, sorted_src, offsets, Wp, agg, N);
    gemm_kernel<<<dim3(MBLK, C_OUT / 64), dim3(256), 0, stream>>>(agg, Wb, b_feat, out, M);
}